// Round 7
// baseline (787.028 us; speedup 1.0000x reference)
//
#include <hip/hip_runtime.h>
#include <hip/hip_fp16.h>

#define TS 524288u
#define NENT (TS * 16u)    // 8388608 entries per feature row
#define FSTR NENT
#define NPTS 1048576u
#define NTHREADS 524288u   // 2048 blocks x 256 = exactly 32 waves/CU residency
#define P1 2654435761u
#define P2 805459861u
#define DMAXL 5            // dense-cell levels 0..5

typedef float f32x4 __attribute__((ext_vector_type(4)));

// SCALINGS = floor(16 * growth^l), growth = 2^(7/15). All exact integers.
__device__ const float SCAL[16] = {
    16.f, 22.f, 30.f, 42.f, 58.f, 80.f, 111.f, 153.f,
    212.f, 294.f, 406.f, 561.f, 776.f, 1072.f, 1482.f, 2048.f
};
// cumulative cell counts R^3 for levels 0..5 (R = 16,22,30,42,58,80)
__device__ const unsigned CCUM[6] = {4096u, 14744u, 41744u, 115832u, 310944u, 822944u};
// cumulative vertex counts (R+1)^3
__device__ const unsigned VCUM[6] = {4913u, 17080u, 46871u, 126378u, 331757u, 863198u};
// uint offsets of each level's cell-block region (8 uints per cell)
__device__ const unsigned DBASE[6] = {0u, 32768u, 117952u, 333952u, 926656u, 2487552u};
// uint offsets of each level's vertex region
__device__ const unsigned VBASE[6] = {0u, 4913u, 17080u, 46871u, 126378u, 331757u};

#define NCELLS 822944u
#define NVERTS 863198u
#define DNB    26334208u   // dense cell bytes  (822944*32)
#define DVB    3452792u    // dense vertex bytes (863198*4)

// fp32 -> bf16 round-to-nearest-even
__device__ inline unsigned bfp(float f) {
    unsigned u = __float_as_uint(f);
    return (u + 0x7FFFu + ((u >> 16) & 1u)) >> 16;
}
__device__ inline float blo(unsigned g) { return __uint_as_float(g << 16); }
__device__ inline float bhi(unsigned g) { return __uint_as_float(g & 0xFFFF0000u); }

// ---- pass 1: pack two fp32 feature rows into bf16x2 (4B/entry) ----
__global__ __launch_bounds__(256) void pack_kernel(
    const float* __restrict__ tab, unsigned* __restrict__ tp)
{
    const unsigned i = (blockIdx.x * 256u + threadIdx.x) * 4u;
    const float4 a = *reinterpret_cast<const float4*>(tab + i);
    const float4 b = *reinterpret_cast<const float4*>(tab + i + FSTR);
    uint4 r;
    r.x = bfp(a.x) | (bfp(b.x) << 16);
    r.y = bfp(a.y) | (bfp(b.y) << 16);
    r.z = bfp(a.z) | (bfp(b.z) << 16);
    r.w = bfp(a.w) | (bfp(b.w) << 16);
    *reinterpret_cast<uint4*>(tp + i) = r;
}

// ---- pass 1b: dense vertex arrays for levels 0..5 (one gather per vertex) ----
__global__ __launch_bounds__(256) void vbuild_kernel(
    const unsigned* __restrict__ tp, unsigned* __restrict__ dv)
{
    const unsigned t = blockIdx.x * 256u + threadIdx.x;
    if (t >= NVERTS) return;
    unsigned lv = 0, base = 0;
#pragma unroll
    for (int l = 0; l < DMAXL; ++l)
        if (t >= VCUM[l]) { lv = l + 1; base = VCUM[l]; }
    const unsigned vid = t - base;
    const unsigned Rp = (unsigned)SCAL[lv] + 1u;
    const unsigned i = vid % Rp;
    const unsigned r1 = vid / Rp;
    const unsigned j = r1 % Rp;
    const unsigned k = r1 / Rp;
    const unsigned h = ((i ^ (j * P1) ^ (k * P2)) & (TS - 1u)) + lv * TS;
    dv[VBASE[lv] + vid] = tp[h];
}

// ---- pass 1c: assemble 32B cell blocks from dense vertices ----
__global__ __launch_bounds__(256) void cbuild_kernel(
    const unsigned* __restrict__ dv, unsigned* __restrict__ dn)
{
    const unsigned t = blockIdx.x * 256u + threadIdx.x;
    if (t >= NCELLS) return;
    unsigned lv = 0, base = 0;
#pragma unroll
    for (int l = 0; l < DMAXL; ++l)
        if (t >= CCUM[l]) { lv = l + 1; base = CCUM[l]; }
    const unsigned cid = t - base;
    const unsigned R = (unsigned)SCAL[lv];
    const unsigned Rp = R + 1u;
    const unsigned B0 = cid % R;
    const unsigned r1 = cid / R;
    const unsigned B1 = r1 % R;
    const unsigned B2 = r1 / R;
    const unsigned* v = dv + VBASE[lv];
    const unsigned vb = (B2 * Rp + B1) * Rp + B0;
    const unsigned sy = Rp, sz = Rp * Rp;
    // word order = SEL rows: (A,A,A),(A,A,B),(A,B,A),(B,A,A),(A,B,B),(B,A,B),(B,B,A),(B,B,B); A=B+1
    const unsigned w0 = v[vb + 1u + sy + sz];
    const unsigned w1 = v[vb + 1u + sy];
    const unsigned w2 = v[vb + 1u + sz];
    const unsigned w3 = v[vb + sy + sz];
    const unsigned w4 = v[vb + 1u];
    const unsigned w5 = v[vb + sy];
    const unsigned w6 = v[vb + sz];
    const unsigned w7 = v[vb];
    uint4* dst = reinterpret_cast<uint4*>(dn + DBASE[lv] + cid * 8u);
    dst[0] = make_uint4(w0, w1, w2, w3);
    dst[1] = make_uint4(w4, w5, w6, w7);
}

// ---- pass 2 (fused): all 16 levels per point in-registers, one coalesced
// 128B output write per point. Grid exactly fills residency (32 waves/CU) so
// all blocks sweep levels in near-lockstep -> ~1 hot table slice in L2.
template <int DENSE>
__global__ __launch_bounds__(256) void fused_kernel(
    const float* __restrict__ x,
    const unsigned* __restrict__ tp,
    const unsigned* __restrict__ dn,
    float* __restrict__ out)
{
    const unsigned t0 = blockIdx.x * 256u + threadIdx.x;
#pragma unroll 1
    for (unsigned c = 0; c < NPTS / NTHREADS; ++c) {
        const unsigned n = t0 + c * NTHREADS;
        const float x0 = x[3u * n + 0u];
        const float x1 = x[3u * n + 1u];
        const float x2 = x[3u * n + 2u];

        __half2 enc[16];
#pragma unroll
        for (int lv = 0; lv < 16; ++lv) {
            const float S = SCAL[lv];
            const float s0 = x0 * S, s1 = x1 * S, s2 = x2 * S;
            const unsigned m = TS - 1u;
            const unsigned tbase = (unsigned)lv * TS;

            unsigned g0, g1, g2, g3, g4, g5, g6, g7;
            if (lv <= DENSE) {
                const float f0 = floorf(s0), f1 = floorf(s1), f2 = floorf(s2);
                const unsigned B0 = (unsigned)(int)f0;
                const unsigned B1 = (unsigned)(int)f1;
                const unsigned B2 = (unsigned)(int)f2;
                const unsigned R = (unsigned)S;
                const unsigned cid = (B2 * R + B1) * R + B0;
                const uint4* blk = reinterpret_cast<const uint4*>(dn + DBASE[lv] + cid * 8u);
                const uint4 lo = blk[0];
                const uint4 hi = blk[1];
                g0 = lo.x; g1 = lo.y; g2 = lo.z; g3 = lo.w;
                g4 = hi.x; g5 = hi.y; g6 = hi.z; g7 = hi.w;
                // rare: s exactly integer -> ceil==floor, block (f,f+1) wrong
                const bool ex = (s0 == f0) | (s1 == f1) | (s2 == f2);
                if (__builtin_expect(__any(ex), 0)) {
                    if (ex) {
                        const unsigned A0 = (unsigned)(int)ceilf(s0);
                        const unsigned a1 = (unsigned)(int)ceilf(s1) * P1, b1 = B1 * P1;
                        const unsigned a2 = (unsigned)(int)ceilf(s2) * P2, b2 = B2 * P2;
                        g0 = tp[((A0 ^ a1 ^ a2) & m) + tbase];
                        g1 = tp[((A0 ^ a1 ^ b2) & m) + tbase];
                        g2 = tp[((A0 ^ b1 ^ a2) & m) + tbase];
                        g3 = tp[((B0 ^ a1 ^ a2) & m) + tbase];
                        g4 = tp[((A0 ^ b1 ^ b2) & m) + tbase];
                        g5 = tp[((B0 ^ a1 ^ b2) & m) + tbase];
                        g6 = tp[((B0 ^ b1 ^ a2) & m) + tbase];
                        g7 = tp[((B0 ^ b1 ^ b2) & m) + tbase];
                    }
                }
            } else {
                const unsigned A0 = (unsigned)(int)ceilf(s0);
                const unsigned B0 = (unsigned)(int)floorf(s0);
                const unsigned a1 = (unsigned)(int)ceilf(s1) * P1;
                const unsigned b1 = (unsigned)(int)floorf(s1) * P1;
                const unsigned a2 = (unsigned)(int)ceilf(s2) * P2;
                const unsigned b2 = (unsigned)(int)floorf(s2) * P2;
                g0 = tp[((A0 ^ a1 ^ a2) & m) + tbase];
                g1 = tp[((A0 ^ a1 ^ b2) & m) + tbase];
                g2 = tp[((A0 ^ b1 ^ a2) & m) + tbase];
                g3 = tp[((B0 ^ a1 ^ a2) & m) + tbase];
                g4 = tp[((A0 ^ b1 ^ b2) & m) + tbase];
                g5 = tp[((B0 ^ a1 ^ b2) & m) + tbase];
                g6 = tp[((B0 ^ b1 ^ a2) & m) + tbase];
                g7 = tp[((B0 ^ b1 ^ b2) & m) + tbase];
            }

            // weights: reference reshape quirk, lv compile-time -> all folded
            float w[3];
#pragma unroll
            for (int i = 0; i < 3; ++i) {
                const int k = lv + 16 * i;
                const int lev = k / 3, dim = k % 3;
                const float xv = (dim == 0) ? x0 : ((dim == 1) ? x1 : x2);
                const float t = xv * SCAL[lev];
                w[i] = t - floorf(t);
            }
            const float wa = w[0], wb = w[1], wc = w[2];
            const float qa = 1.f - wa, qb = 1.f - wb, qc = 1.f - wc;

            const float e0 = ((blo(g0) * wa + blo(g3) * qa) * wb + (blo(g1) * wa + blo(g2) * qa) * qb) * wc
                           + ((blo(g4) * wa + blo(g7) * qa) * wb + (blo(g5) * wa + blo(g6) * qa) * qb) * qc;
            const float e1 = ((bhi(g0) * wa + bhi(g3) * qa) * wb + (bhi(g1) * wa + bhi(g2) * qa) * qb) * wc
                           + ((bhi(g4) * wa + bhi(g7) * qa) * wb + (bhi(g5) * wa + bhi(g6) * qa) * qb) * qc;
            enc[lv] = __floats2half2_rn(e0, e1);
        }

        // one contiguous 128B write per point; nontemporal -> don't evict table
        f32x4* o = reinterpret_cast<f32x4*>(out + (size_t)n * 32u);
#pragma unroll
        for (int k = 0; k < 8; ++k) {
            const float2 a = __half22float2(enc[2 * k]);
            const float2 b = __half22float2(enc[2 * k + 1]);
            f32x4 v = {a.x, a.y, b.x, b.y};
            __builtin_nontemporal_store(v, o + k);
        }
    }
}

// ---- last-resort fallback: no workspace (round-1 kernel) ----
__global__ __launch_bounds__(256) void hashenc_fallback(
    const float* __restrict__ x,
    const float* __restrict__ tab,
    float2* __restrict__ out)
{
    const unsigned tid = blockIdx.x * 256u + threadIdx.x;
    const unsigned n = tid >> 4;
    const unsigned l = tid & 15u;
    const float x0 = x[3u * n], x1 = x[3u * n + 1u], x2 = x[3u * n + 2u];
    const float S = SCAL[l];
    const float s0 = x0 * S, s1 = x1 * S, s2 = x2 * S;
    const unsigned A0 = (unsigned)(int)ceilf(s0);
    const unsigned B0 = (unsigned)(int)floorf(s0);
    const unsigned a1 = (unsigned)(int)ceilf(s1) * P1;
    const unsigned b1 = (unsigned)(int)floorf(s1) * P1;
    const unsigned a2 = (unsigned)(int)ceilf(s2) * P2;
    const unsigned b2 = (unsigned)(int)floorf(s2) * P2;
    const unsigned m = TS - 1u;
    const unsigned base = l * TS;
    const unsigned i0 = ((A0 ^ a1 ^ a2) & m) + base;
    const unsigned i1 = ((A0 ^ a1 ^ b2) & m) + base;
    const unsigned i2 = ((A0 ^ b1 ^ a2) & m) + base;
    const unsigned i3 = ((B0 ^ a1 ^ a2) & m) + base;
    const unsigned i4 = ((A0 ^ b1 ^ b2) & m) + base;
    const unsigned i5 = ((B0 ^ a1 ^ b2) & m) + base;
    const unsigned i6 = ((B0 ^ b1 ^ a2) & m) + base;
    const unsigned i7 = ((B0 ^ b1 ^ b2) & m) + base;
    const float a0v = tab[i0], a1v = tab[i1], a2v = tab[i2], a3v = tab[i3];
    const float a4v = tab[i4], a5v = tab[i5], a6v = tab[i6], a7v = tab[i7];
    const float b0v = tab[i0 + FSTR], b1v = tab[i1 + FSTR], b2v = tab[i2 + FSTR], b3v = tab[i3 + FSTR];
    const float b4v = tab[i4 + FSTR], b5v = tab[i5 + FSTR], b6v = tab[i6 + FSTR], b7v = tab[i7 + FSTR];
    float w[3];
#pragma unroll
    for (int i = 0; i < 3; ++i) {
        const unsigned k = l + 16u * i;
        const unsigned lev = k / 3u, dim = k % 3u;
        const float xv = (dim == 0u) ? x0 : ((dim == 1u) ? x1 : x2);
        const float t = xv * SCAL[lev];
        w[i] = t - floorf(t);
    }
    const float wa = w[0], wb = w[1], wc = w[2];
    const float qa = 1.f - wa, qb = 1.f - wb, qc = 1.f - wc;
    const float e0 = ((a0v * wa + a3v * qa) * wb + (a1v * wa + a2v * qa) * qb) * wc
                   + ((a4v * wa + a7v * qa) * wb + (a5v * wa + a6v * qa) * qb) * qc;
    const float e1 = ((b0v * wa + b3v * qa) * wb + (b1v * wa + b2v * qa) * qb) * wc
                   + ((b4v * wa + b7v * qa) * wb + (b5v * wa + b6v * qa) * qb) * qc;
    out[tid] = make_float2(e0, e1);
}

extern "C" void kernel_launch(void* const* d_in, const int* in_sizes, int n_in,
                              void* d_out, int out_size, void* d_ws, size_t ws_size,
                              hipStream_t stream) {
    const float* x   = (const float*)d_in[0];
    const float* tab = (const float*)d_in[1];
    char* ws = (char*)d_ws;

    const size_t packB = (size_t)NENT * 4u;                       // 32 MB
    const size_t need_dense = packB + (size_t)DNB + (size_t)DVB;  // ~62 MB
    const size_t need_plain = packB;

    if (ws_size >= need_dense) {
        unsigned* tp = (unsigned*)ws;
        unsigned* dn = (unsigned*)(ws + packB);
        unsigned* dv = (unsigned*)(ws + packB + DNB);
        pack_kernel<<<NENT / 4u / 256u, 256, 0, stream>>>(tab, tp);
        vbuild_kernel<<<(NVERTS + 255u) / 256u, 256, 0, stream>>>(tp, dv);
        cbuild_kernel<<<(NCELLS + 255u) / 256u, 256, 0, stream>>>(dv, dn);
        fused_kernel<DMAXL><<<NTHREADS / 256u, 256, 0, stream>>>(x, tp, dn, (float*)d_out);
    } else if (ws_size >= need_plain) {
        unsigned* tp = (unsigned*)ws;
        pack_kernel<<<NENT / 4u / 256u, 256, 0, stream>>>(tab, tp);
        fused_kernel<-1><<<NTHREADS / 256u, 256, 0, stream>>>(x, tp, tp, (float*)d_out);
    } else {
        hashenc_fallback<<<NPTS * 16u / 256u, 256, 0, stream>>>(x, tab, (float2*)d_out);
    }
}